// Round 16
// baseline (129.690 us; speedup 1.0000x reference)
//
#include <hip/hip_runtime.h>
#include <math.h>

#define NROWS 65536
#define D     64
#define K     1024
#define NCT   8            // code tiles (K/128)
#define BR    64           // rows per block (wave = 16 rows)
#define BC    128
#define BETA  0.25f
#define SCALE 1024.0f      // pow2 -> exact f32 scaling; keeps xl/el f16-normal
#define THR   200.0f       // scaled-dist margin (~1.9e-4 unscaled; ~40x filter err)

typedef _Float16 half8  __attribute__((ext_vector_type(8)));
typedef _Float16 half4v __attribute__((ext_vector_type(4)));
typedef float    f32x4  __attribute__((ext_vector_type(4)));
typedef unsigned long long u64;

// ws layout (bytes) -- total < 800 KB
#define WS_BP   0u                         // f16 [K][128]: cols 0-63 eh, 64-127 el (256 KB)
#define WS_EN   (256u*1024)                // f32 [K] (4 KB)
#define WS_FID  (WS_EN + 4u*1024)          // u32 [NROWS] (256 KB)
#define WS_LIST (WS_FID + 256u*1024)       // u32 [NROWS] (256 KB)
#define WS_CNT  (WS_LIST + 256u*1024)      // u32 counter (pad 256)
#define WS_PART (WS_CNT + 256u)            // f32 [256]

static __device__ __forceinline__ unsigned ordf(float f) {
    unsigned b = __float_as_uint(f);
    return (b & 0x80000000u) ? ~b : (b | 0x80000000u);
}
static __device__ __forceinline__ float unordf(unsigned u) {
    unsigned b = (u & 0x80000000u) ? (u & 0x7FFFFFFFu) : ~u;
    return __uint_as_float(b);
}
static __device__ __forceinline__ u64 umin64(u64 a, u64 b) { return a < b ? a : b; }
static __device__ __forceinline__ u64 umax64(u64 a, u64 b) { return a < b ? b : a; }

// ---------------------------------------------------- prep: enorm + packed B
__global__ __launch_bounds__(256) void vq_prep(const float* __restrict__ emb,
                                               float* __restrict__ enorm,
                                               _Float16* __restrict__ Bp,
                                               unsigned* __restrict__ counter) {
    if (blockIdx.x == 0 && threadIdx.x == 0) counter[0] = 0u;   // fresh each launch
    int k = blockIdx.x * 256 + threadIdx.x;
    if (k >= K) return;
    const float4* e4 = (const float4*)(emb + (size_t)k * D);
    _Float16* bp = Bp + (size_t)k * 128;
    float s = 0.f;
    #pragma unroll
    for (int i = 0; i < 16; ++i) {
        float4 e = e4[i];
        s += e.x * e.x + e.y * e.y + e.z * e.z + e.w * e.w;   // R1-order enorm
        float c0 = e.x * SCALE, c1 = e.y * SCALE, c2 = e.z * SCALE, c3 = e.w * SCALE;
        _Float16 h0 = (_Float16)c0, h1 = (_Float16)c1, h2 = (_Float16)c2, h3 = (_Float16)c3;
        bp[i*4+0] = h0; bp[64+i*4+0] = (_Float16)(c0 - (float)h0);
        bp[i*4+1] = h1; bp[64+i*4+1] = (_Float16)(c1 - (float)h1);
        bp[i*4+2] = h2; bp[64+i*4+2] = (_Float16)(c2 - (float)h2);
        bp[i*4+3] = h3; bp[64+i*4+3] = (_Float16)(c3 - (float)h3);
    }
    enorm[k] = s;
}

// ---------------------------- fused MFMA filter (R15-proven math, new shape)
// BR=64: wave = 16 rows x 128 cols (8 ci fragments). A frags (xh,xl) in
// REGISTERS (staged through the B LDS buffers, read once). Per tile: stage B
// (stride-32 u64, R15-proven), 2x{read bh x8 -> ah*bh, al*bh; read bl x8 ->
// ah*bl}, then tournament-tree top-2 per rg. LDS 37.4 KB -> 4 blocks/CU.
__global__ __launch_bounds__(256, 3) void vq_gemm(const float* __restrict__ x,
                                                  const _Float16* __restrict__ Bp,
                                                  const float* __restrict__ enorm,
                                                  unsigned* __restrict__ fid,
                                                  unsigned* __restrict__ list,
                                                  unsigned* __restrict__ counter) {
    __shared__ _Float16 bSh[BC][72];           // 18.4 KB; also stages A=xh
    __shared__ _Float16 bSl[BC][72];           // 18.4 KB; also stages A=xl
    __shared__ float    en2[BC];               // 0.5 KB

    const int tid = threadIdx.x;
    const int rb  = (int)blockIdx.x * BR;

    // ---- stage A (xh -> bSh rows 0..63, xl -> bSl rows 0..63) ----
    const float4* x4 = (const float4*)x;
    #pragma unroll
    for (int p = 0; p < 4; ++p) {
        int q = p * 256 + tid;                 // 0..1023
        int r = q >> 4, c4 = q & 15;
        float4 v = x4[(size_t)(rb + r) * 16 + c4];
        float s0 = v.x * SCALE, s1 = v.y * SCALE, s2 = v.z * SCALE, s3 = v.w * SCALE;
        _Float16 h0 = (_Float16)s0, h1 = (_Float16)s1, h2 = (_Float16)s2, h3 = (_Float16)s3;
        half4v hh; hh[0] = h0; hh[1] = h1; hh[2] = h2; hh[3] = h3;
        half4v hl;
        hl[0] = (_Float16)(s0 - (float)h0); hl[1] = (_Float16)(s1 - (float)h1);
        hl[2] = (_Float16)(s2 - (float)h2); hl[3] = (_Float16)(s3 - (float)h3);
        *(half4v*)&bSh[r][c4 * 4] = hh;
        *(half4v*)&bSl[r][c4 * 4] = hl;
    }
    __syncthreads();

    const int lane = tid & 63, w = tid >> 6;
    const int fr = lane & 15;                  // frag row (A) / frag col (B)
    const int kg = lane >> 4;                  // k-group 0..3

    // ---- A fragments to registers (once; same addresses R15 read per-chunk)
    half8 ah[2], al[2];
    #pragma unroll
    for (int kk = 0; kk < 2; ++kk) {
        ah[kk] = *(const half8*)&bSh[w * 16 + fr][kk * 32 + kg * 8];
        al[kk] = *(const half8*)&bSl[w * 16 + fr][kk * 32 + kg * 8];
    }
    __syncthreads();                           // A reads done; buffers -> B

    u64 b1[4], b2[4];                          // running top-2 per rg
    #pragma unroll
    for (int rg = 0; rg < 4; ++rg) { b1[rg] = ~0ull; b2[rg] = ~0ull; }

    const u64* bp64 = (const u64*)Bp;

    for (int ct = 0; ct < NCT; ++ct) {
        const int cb = ct * BC;
        __syncthreads();                       // protect b-buffers reuse
        // stage B: rows are 32 u64 (256 B) each (stride-32: R15-proven)
        #pragma unroll
        for (int p = 0; p < 16; ++p) {
            int q = p * 256 + tid;             // 0..4095
            int r = q >> 5, c = q & 31;
            u64 v = bp64[(size_t)(cb + r) * 32 + c];
            if (c < 16) *(u64*)&bSh[r][c * 4] = v;
            else        *(u64*)&bSl[r][(c - 16) * 4] = v;
        }
        if (tid < BC) en2[tid] = enorm[cb + tid] * (SCALE * SCALE);  // pow2: exact
        __syncthreads();

        f32x4 acc[8];
        #pragma unroll
        for (int ci = 0; ci < 8; ++ci) acc[ci] = (f32x4){0.f, 0.f, 0.f, 0.f};

        #pragma unroll
        for (int kk = 0; kk < 2; ++kk) {
            half8 bf[8];
            #pragma unroll
            for (int ci = 0; ci < 8; ++ci)     // bh frags
                bf[ci] = *(const half8*)&bSh[ci * 16 + fr][kk * 32 + kg * 8];
            #pragma unroll
            for (int ci = 0; ci < 8; ++ci) {   // xh*eh + xl*eh (bh reused)
                acc[ci] = __builtin_amdgcn_mfma_f32_16x16x32_f16(ah[kk], bf[ci], acc[ci], 0, 0, 0);
                acc[ci] = __builtin_amdgcn_mfma_f32_16x16x32_f16(al[kk], bf[ci], acc[ci], 0, 0, 0);
            }
            #pragma unroll
            for (int ci = 0; ci < 8; ++ci)     // bl frags
                bf[ci] = *(const half8*)&bSl[ci * 16 + fr][kk * 32 + kg * 8];
            #pragma unroll
            for (int ci = 0; ci < 8; ++ci)     // xh*el
                acc[ci] = __builtin_amdgcn_mfma_f32_16x16x32_f16(ah[kk], bf[ci], acc[ci], 0, 0, 0);
        }

        float en2f[8];
        #pragma unroll
        for (int ci = 0; ci < 8; ++ci) en2f[ci] = en2[ci * 16 + fr];

        // tournament-tree top-2 per rg, then one running merge (shallow deps)
        #pragma unroll
        for (int rg = 0; rg < 4; ++rg) {
            u64 pk[8];
            #pragma unroll
            for (int ci = 0; ci < 8; ++ci) {
                float r = fmaf(-2.f, acc[ci][rg], en2f[ci]);
                pk[ci] = ((u64)ordf(r) << 32) | (unsigned)(cb + ci * 16 + fr);
            }
            u64 s1a = umin64(pk[0], pk[1]), s2a = umax64(pk[0], pk[1]);
            u64 s1b = umin64(pk[2], pk[3]), s2b = umax64(pk[2], pk[3]);
            u64 s1c = umin64(pk[4], pk[5]), s2c = umax64(pk[4], pk[5]);
            u64 s1d = umin64(pk[6], pk[7]), s2d = umax64(pk[6], pk[7]);
            u64 m1ab = umin64(s1a, s1b);
            u64 m2ab = umin64(umax64(s1a, s1b), umin64(s2a, s2b));
            u64 m1cd = umin64(s1c, s1d);
            u64 m2cd = umin64(umax64(s1c, s1d), umin64(s2c, s2d));
            u64 t1 = umin64(m1ab, m1cd);
            u64 t2 = umin64(umax64(m1ab, m1cd), umin64(m2ab, m2cd));
            u64 nb2 = umin64(umax64(b1[rg], t1), umin64(b2[rg], t2));
            b1[rg] = umin64(b1[rg], t1);
            b2[rg] = nb2;
        }
    }

    // final: butterfly top-2 across the 16 fr lanes, margin test, write
    #pragma unroll
    for (int rg = 0; rg < 4; ++rg) {
        u64 v1 = b1[rg], v2 = b2[rg];
        #pragma unroll
        for (int off = 8; off >= 1; off >>= 1) {
            u64 o1 = (u64)__shfl_xor((long long)v1, off, 16);
            u64 o2 = (u64)__shfl_xor((long long)v2, off, 16);
            u64 n2 = umin64(umax64(v1, o1), umin64(v2, o2));
            v1 = umin64(v1, o1);
            v2 = n2;
        }
        if (fr == 0) {
            int row = rb + w * 16 + kg * 4 + rg;
            float f1 = unordf((unsigned)(v1 >> 32));
            float f2 = unordf((unsigned)(v2 >> 32));
            if (f2 - f1 > THR) {
                fid[row] = (unsigned)(v1 & 0xFFFFFFFFu);  // provably ref argmin
            } else {
                unsigned pos = atomicAdd(counter, 1u);
                list[pos] = (unsigned)row;
            }
        }
    }
}

// --------------------------- exact fallback: full 1024-code scan, R1 form ---
__global__ __launch_bounds__(256) void vq_fallback(const float* __restrict__ x,
                                                   const float* __restrict__ emb,
                                                   const float* __restrict__ enorm,
                                                   const unsigned* __restrict__ list,
                                                   const unsigned* __restrict__ counter,
                                                   unsigned* __restrict__ final_idx) {
    __shared__ float4 xr[16];
    __shared__ u64 red[256];
    const int tid = threadIdx.x;
    const unsigned total = counter[0];
    for (unsigned i = blockIdx.x; i < total; i += gridDim.x) {
        const int n = (int)list[i];
        __syncthreads();
        if (tid < 16) xr[tid] = ((const float4*)x)[(size_t)n * 16 + tid];
        __syncthreads();
        float xnorm = 0.f;                     // R1-order xnorm
        #pragma unroll
        for (int q = 0; q < 16; ++q) {
            float4 v = xr[q];
            xnorm += v.x * v.x + v.y * v.y + v.z * v.z + v.w * v.w;
        }
        u64 best = ~0ull;
        #pragma unroll
        for (int j = 0; j < 4; ++j) {
            int k = tid + j * 256;
            const float4* e4 = (const float4*)(emb + (size_t)k * D);
            float d0 = 0.f, d1 = 0.f, d2 = 0.f, d3 = 0.f;
            #pragma unroll
            for (int q = 0; q < 4; ++q) {      // proven R1 4-chain ordering
                float4 ea = e4[q*4+0], eb = e4[q*4+1], ec = e4[q*4+2], ed = e4[q*4+3];
                float4 va = xr[q*4+0], vb = xr[q*4+1], vc = xr[q*4+2], vd = xr[q*4+3];
                d0 = fmaf(va.w, ea.w, fmaf(va.z, ea.z, fmaf(va.y, ea.y, fmaf(va.x, ea.x, d0))));
                d1 = fmaf(vb.w, eb.w, fmaf(vb.z, eb.z, fmaf(vb.y, eb.y, fmaf(vb.x, eb.x, d1))));
                d2 = fmaf(vc.w, ec.w, fmaf(vc.z, ec.z, fmaf(vc.y, ec.y, fmaf(vc.x, ec.x, d2))));
                d3 = fmaf(vd.w, ed.w, fmaf(vd.z, ed.z, fmaf(vd.y, ed.y, fmaf(vd.x, ed.x, d3))));
            }
            float dot  = (d0 + d1) + (d2 + d3);
            float dist = fmaf(-2.f, dot, xnorm + enorm[k]);
            u64 pk = ((u64)ordf(dist) << 32) | (unsigned)k;
            if (pk < best) best = pk;          // dist-then-lowest-idx
        }
        red[tid] = best;
        __syncthreads();
        for (int s = 128; s > 0; s >>= 1) {
            if (tid < s) red[tid] = red[tid] < red[tid+s] ? red[tid] : red[tid+s];
            __syncthreads();
        }
        if (tid == 0) final_idx[n] = (unsigned)(red[0] & 0xFFFFFFFFu);
    }
}

// ------------------------------------------------------ gather + loss ------
__global__ __launch_bounds__(256) void vq_out(const float* __restrict__ x,
                                              const float* __restrict__ emb,
                                              const unsigned* __restrict__ final_idx,
                                              float* __restrict__ out,
                                              float* __restrict__ partial) {
    __shared__ int   lds_idx[256];
    __shared__ float lds_red[256];
    const int tid   = threadIdx.x;
    const int rbase = blockIdx.x * 256;
    const int n     = rbase + tid;

    lds_idx[tid] = (int)(final_idx[n] & 0xFFFFu);
    __syncthreads();

    const float4* x4 = (const float4*)x;
    const float4* e4 = (const float4*)emb;
    float4* o4 = (float4*)out;
    float err = 0.f;
    #pragma unroll
    for (int i = 0; i < 16; ++i) {
        int f = i * 256 + tid;
        int row = f >> 4, col = f & 15;
        int e = lds_idx[row];
        float4 q = e4[(size_t)e * 16 + col];
        float4 v = x4[(size_t)rbase * 16 + f];
        float ax = q.x - v.x, ay = q.y - v.y, az = q.z - v.z, aw = q.w - v.w;
        err += ax * ax + ay * ay + az * az + aw * aw;
        o4[(size_t)rbase * 16 + f] = q;
    }
    __syncthreads();
    lds_red[tid] = err;
    __syncthreads();
    for (int s = 128; s > 0; s >>= 1) {
        if (tid < s) lds_red[tid] += lds_red[tid + s];
        __syncthreads();
    }
    if (tid == 0) partial[blockIdx.x] = lds_red[0];
}

// ------------------------------------------------------------- finalize ----
__global__ __launch_bounds__(256) void vq_finish(const float* __restrict__ partial,
                                                 float* __restrict__ loss_out) {
    __shared__ float lds[256];
    int tid = threadIdx.x;
    lds[tid] = partial[tid];
    __syncthreads();
    for (int s = 128; s > 0; s >>= 1) {
        if (tid < s) lds[tid] += lds[tid + s];
        __syncthreads();
    }
    if (tid == 0) loss_out[0] = (1.0f + BETA) * lds[0] / (float)(NROWS * D);
}

// ---------------------------------------------------------------- launch ---
extern "C" void kernel_launch(void* const* d_in, const int* in_sizes, int n_in,
                              void* d_out, int out_size, void* d_ws, size_t ws_size,
                              hipStream_t stream) {
    const float* x   = (const float*)d_in[0];
    const float* emb = (const float*)d_in[1];
    float* out = (float*)d_out;
    char* ws = (char*)d_ws;

    _Float16* Bp      = (_Float16*)(ws + WS_BP);
    float* enorm      = (float*)(ws + WS_EN);
    unsigned* fid     = (unsigned*)(ws + WS_FID);
    unsigned* list    = (unsigned*)(ws + WS_LIST);
    unsigned* counter = (unsigned*)(ws + WS_CNT);
    float* partial    = (float*)(ws + WS_PART);

    vq_prep<<<K / 256, 256, 0, stream>>>(emb, enorm, Bp, counter);
    vq_gemm<<<NROWS / BR, 256, 0, stream>>>(x, Bp, enorm, fid, list, counter);
    vq_fallback<<<128, 256, 0, stream>>>(x, emb, enorm, list, counter, fid);
    vq_out<<<NROWS / 256, 256, 0, stream>>>(x, emb, fid, out, partial);
    vq_finish<<<1, 256, 0, stream>>>(partial, out + (size_t)NROWS * D);
}

// Round 17
// 81.983 us; speedup vs baseline: 1.5819x; 1.5819x over previous
//
#include <hip/hip_runtime.h>
#include <math.h>

#define NROWS 65536
#define D     64
#define K     1024
#define NCT   8            // code tiles (K/128)
#define BR    128
#define BC    128
#define BETA  0.25f
#define SCALE 1024.0f      // pow2 -> exact f32 scaling; keeps xl/el f16-normal
#define THR   200.0f       // scaled-dist margin (R15-proven)

typedef _Float16 half8  __attribute__((ext_vector_type(8)));
typedef float    f32x4  __attribute__((ext_vector_type(4)));
typedef unsigned long long u64;

// ws layout (bytes)
// Bp: per code-tile ct, a 32 KB block that is the EXACT LDS image:
//   [bh 16 KB: row r (0..127) x chunk c' (16B), c' = c ^ (r&7)][bl 16 KB same]
#define WS_BP   0u                         // 8 tiles x 32 KB = 256 KB
#define WS_EN   (256u*1024)                // f32 [K] (4 KB)
#define WS_FID  (WS_EN + 4u*1024)          // u32 [NROWS] (256 KB)
#define WS_LIST (WS_FID + 256u*1024)       // u32 [NROWS] (256 KB)
#define WS_CNT  (WS_LIST + 256u*1024)      // u32 counter
#define WS_PART (WS_CNT + 256u)            // f32 [256]

static __device__ __forceinline__ unsigned ordf(float f) {
    unsigned b = __float_as_uint(f);
    return (b & 0x80000000u) ? ~b : (b | 0x80000000u);
}
static __device__ __forceinline__ float unordf(unsigned u) {
    unsigned b = (u & 0x80000000u) ? (u & 0x7FFFFFFFu) : ~u;
    return __uint_as_float(b);
}
static __device__ __forceinline__ u64 umin64(u64 a, u64 b) { return a < b ? a : b; }
static __device__ __forceinline__ u64 umax64(u64 a, u64 b) { return a < b ? b : a; }

static __device__ __forceinline__ void gload_lds16(const void* g, void* l) {
    __builtin_amdgcn_global_load_lds(
        (const __attribute__((address_space(1))) unsigned*)g,
        (__attribute__((address_space(3))) unsigned*)l,
        16, 0, 0);
}

// ------------------- prep: enorm + swizzled/tiled packed B + counter reset --
__global__ __launch_bounds__(256) void vq_prep(const float* __restrict__ emb,
                                               float* __restrict__ enorm,
                                               char* __restrict__ Bp,
                                               unsigned* __restrict__ counter) {
    if (blockIdx.x == 0 && threadIdx.x == 0) counter[0] = 0u;   // fresh each launch
    int k = blockIdx.x * 256 + threadIdx.x;
    if (k >= K) return;
    const int ct = k >> 7, r = k & 127;
    char* base = Bp + (size_t)ct * 32768 + (size_t)r * 128;
    const float4* e4 = (const float4*)(emb + (size_t)k * D);
    float s = 0.f;
    #pragma unroll
    for (int c = 0; c < 8; ++c) {              // chunk c = f16 elems 8c..8c+7
        float4 ea = e4[2 * c], eb = e4[2 * c + 1];
        s += ea.x * ea.x + ea.y * ea.y + ea.z * ea.z + ea.w * ea.w;   // R1-order
        s += eb.x * eb.x + eb.y * eb.y + eb.z * eb.z + eb.w * eb.w;
        float sc[8] = {ea.x * SCALE, ea.y * SCALE, ea.z * SCALE, ea.w * SCALE,
                       eb.x * SCALE, eb.y * SCALE, eb.z * SCALE, eb.w * SCALE};
        half8 hh, hl;
        #pragma unroll
        for (int e = 0; e < 8; ++e) {
            _Float16 h = (_Float16)sc[e];
            hh[e] = h;
            hl[e] = (_Float16)(sc[e] - (float)h);
        }
        int off = ((c ^ (r & 7)) << 4);
        *(half8*)(base + off)         = hh;     // eh
        *(half8*)(base + 16384 + off) = hl;     // el
    }
    enorm[k] = s;
}

// --------------- MFMA filter: BR=128, dbuf LDS via global_load_lds, A in regs
// dot ~ xh*eh + xh*el + xl*eh (R15-proven split + THR margin). 4 waves, wave =
// 32 rows x 128 codes (2 fi x 8 ci 16x16x32 frags), acc in ci-groups of 4.
// One barrier/tile; prefetch next B tile async during compute.
__global__ __launch_bounds__(256, 2) void vq_gemm(const float* __restrict__ x,
                                                  const char* __restrict__ Bp,
                                                  const float* __restrict__ enorm,
                                                  unsigned* __restrict__ fid,
                                                  unsigned* __restrict__ list,
                                                  unsigned* __restrict__ counter) {
    __shared__ __align__(16) char bufB[2][32768];   // 64 KB double buffer

    const int tid  = threadIdx.x;
    const int lane = tid & 63, w = tid >> 6;
    const int fr   = lane & 15;                // frag row (A) / frag col (B)
    const int kg   = lane >> 4;                // k-group 0..3
    const int rb   = (int)blockIdx.x * BR;

    // ---- A fragments: direct global load + scale/split in registers ----
    const float4* x4 = (const float4*)x;
    half8 ah[2][2], al[2][2];
    #pragma unroll
    for (int fi = 0; fi < 2; ++fi) {
        #pragma unroll
        for (int kk = 0; kk < 2; ++kk) {
            int row = rb + w * 32 + fi * 16 + fr;
            float4 v0 = x4[(size_t)row * 16 + kk * 8 + kg * 2];
            float4 v1 = x4[(size_t)row * 16 + kk * 8 + kg * 2 + 1];
            float sc[8] = {v0.x * SCALE, v0.y * SCALE, v0.z * SCALE, v0.w * SCALE,
                           v1.x * SCALE, v1.y * SCALE, v1.z * SCALE, v1.w * SCALE};
            #pragma unroll
            for (int e = 0; e < 8; ++e) {
                _Float16 h = (_Float16)sc[e];
                ah[fi][kk][e] = h;
                al[fi][kk][e] = (_Float16)(sc[e] - (float)h);
            }
        }
    }

    // ---- prefetch B tile 0 ----
    {
        const char* gsrc = Bp + (size_t)w * 8192 + (size_t)lane * 16;
        char* ldst = &bufB[0][w * 8192];
        #pragma unroll
        for (int j = 0; j < 8; ++j)
            gload_lds16(gsrc + j * 1024, ldst + j * 1024);
    }

    u64 b1[2][4], b2[2][4];                    // running top-2 per (fi,rg)
    #pragma unroll
    for (int fi = 0; fi < 2; ++fi)
        #pragma unroll
        for (int rg = 0; rg < 4; ++rg) { b1[fi][rg] = ~0ull; b2[fi][rg] = ~0ull; }

    for (int ct = 0; ct < NCT; ++ct) {
        const int  cb  = ct * BC;
        const int  buf = ct & 1;
        __syncthreads();                       // drains B(ct) gl_lds; separates buf reuse

        if (ct < NCT - 1) {                    // prefetch B(ct+1), lands by next barrier
            const char* gsrc = Bp + (size_t)(ct + 1) * 32768 + (size_t)w * 8192
                             + (size_t)lane * 16;
            char* ldst = &bufB[buf ^ 1][w * 8192];
            #pragma unroll
            for (int j = 0; j < 8; ++j)
                gload_lds16(gsrc + j * 1024, ldst + j * 1024);
        }

        float en2f[8];
        #pragma unroll
        for (int ci = 0; ci < 8; ++ci)         // per-lane, L1/L2-cached
            en2f[ci] = enorm[cb + ci * 16 + fr] * (SCALE * SCALE);

        const char* bb = &bufB[buf][0];

        #pragma unroll
        for (int g = 0; g < 2; ++g) {          // ci-groups of 4 (caps VGPR)
            f32x4 acc[2][4];
            #pragma unroll
            for (int fi = 0; fi < 2; ++fi)
                #pragma unroll
                for (int i = 0; i < 4; ++i) acc[fi][i] = (f32x4){0.f, 0.f, 0.f, 0.f};

            #pragma unroll
            for (int kk = 0; kk < 2; ++kk) {
                const int chunk = ((kk * 4 + kg) ^ (fr & 7)) << 4;
                half8 bf[4];
                #pragma unroll
                for (int i = 0; i < 4; ++i)    // bh frags (swizzled, ~2-way free)
                    bf[i] = *(const half8*)(bb + ((g * 4 + i) * 16 + fr) * 128 + chunk);
                #pragma unroll
                for (int i = 0; i < 4; ++i) {
                    #pragma unroll
                    for (int fi = 0; fi < 2; ++fi) {
                        acc[fi][i] = __builtin_amdgcn_mfma_f32_16x16x32_f16(ah[fi][kk], bf[i], acc[fi][i], 0, 0, 0);
                        acc[fi][i] = __builtin_amdgcn_mfma_f32_16x16x32_f16(al[fi][kk], bf[i], acc[fi][i], 0, 0, 0);
                    }
                }
                #pragma unroll
                for (int i = 0; i < 4; ++i)    // bl frags
                    bf[i] = *(const half8*)(bb + 16384 + ((g * 4 + i) * 16 + fr) * 128 + chunk);
                #pragma unroll
                for (int i = 0; i < 4; ++i)
                    #pragma unroll
                    for (int fi = 0; fi < 2; ++fi)
                        acc[fi][i] = __builtin_amdgcn_mfma_f32_16x16x32_f16(ah[fi][kk], bf[i], acc[fi][i], 0, 0, 0);
            }

            // top-2 tournament (4 elems) + running merge, per (fi,rg)
            #pragma unroll
            for (int fi = 0; fi < 2; ++fi) {
                #pragma unroll
                for (int rg = 0; rg < 4; ++rg) {
                    u64 pk[4];
                    #pragma unroll
                    for (int i = 0; i < 4; ++i) {
                        float r = fmaf(-2.f, acc[fi][i][rg], en2f[g * 4 + i]);
                        pk[i] = ((u64)ordf(r) << 32) | (unsigned)(cb + (g * 4 + i) * 16 + fr);
                    }
                    u64 s1a = umin64(pk[0], pk[1]), s2a = umax64(pk[0], pk[1]);
                    u64 s1b = umin64(pk[2], pk[3]), s2b = umax64(pk[2], pk[3]);
                    u64 t1  = umin64(s1a, s1b);
                    u64 t2  = umin64(umax64(s1a, s1b), umin64(s2a, s2b));
                    u64 nb2 = umin64(umax64(b1[fi][rg], t1), umin64(b2[fi][rg], t2));
                    b1[fi][rg] = umin64(b1[fi][rg], t1);
                    b2[fi][rg] = nb2;
                }
            }
        }
    }

    // final: butterfly top-2 across the 16 fr lanes, margin test, write
    #pragma unroll
    for (int fi = 0; fi < 2; ++fi) {
        #pragma unroll
        for (int rg = 0; rg < 4; ++rg) {
            u64 v1 = b1[fi][rg], v2 = b2[fi][rg];
            #pragma unroll
            for (int off = 8; off >= 1; off >>= 1) {
                u64 o1 = (u64)__shfl_xor((long long)v1, off, 16);
                u64 o2 = (u64)__shfl_xor((long long)v2, off, 16);
                u64 n2 = umin64(umax64(v1, o1), umin64(v2, o2));
                v1 = umin64(v1, o1);
                v2 = n2;
            }
            if (fr == 0) {
                int row = rb + w * 32 + fi * 16 + kg * 4 + rg;
                float f1 = unordf((unsigned)(v1 >> 32));
                float f2 = unordf((unsigned)(v2 >> 32));
                if (f2 - f1 > THR) {
                    fid[row] = (unsigned)(v1 & 0xFFFFFFFFu);  // provably ref argmin
                } else {
                    unsigned pos = atomicAdd(counter, 1u);
                    list[pos] = (unsigned)row;
                }
            }
        }
    }
}

// --------------------------- exact fallback: full 1024-code scan, R1 form ---
__global__ __launch_bounds__(256) void vq_fallback(const float* __restrict__ x,
                                                   const float* __restrict__ emb,
                                                   const float* __restrict__ enorm,
                                                   const unsigned* __restrict__ list,
                                                   const unsigned* __restrict__ counter,
                                                   unsigned* __restrict__ final_idx) {
    __shared__ float4 xr[16];
    __shared__ u64 red[256];
    const int tid = threadIdx.x;
    const unsigned total = counter[0];
    for (unsigned i = blockIdx.x; i < total; i += gridDim.x) {
        const int n = (int)list[i];
        __syncthreads();
        if (tid < 16) xr[tid] = ((const float4*)x)[(size_t)n * 16 + tid];
        __syncthreads();
        float xnorm = 0.f;                     // R1-order xnorm
        #pragma unroll
        for (int q = 0; q < 16; ++q) {
            float4 v = xr[q];
            xnorm += v.x * v.x + v.y * v.y + v.z * v.z + v.w * v.w;
        }
        u64 best = ~0ull;
        #pragma unroll
        for (int j = 0; j < 4; ++j) {
            int k = tid + j * 256;
            const float4* e4 = (const float4*)(emb + (size_t)k * D);
            float d0 = 0.f, d1 = 0.f, d2 = 0.f, d3 = 0.f;
            #pragma unroll
            for (int q = 0; q < 4; ++q) {      // proven R1 4-chain ordering
                float4 ea = e4[q*4+0], eb = e4[q*4+1], ec = e4[q*4+2], ed = e4[q*4+3];
                float4 va = xr[q*4+0], vb = xr[q*4+1], vc = xr[q*4+2], vd = xr[q*4+3];
                d0 = fmaf(va.w, ea.w, fmaf(va.z, ea.z, fmaf(va.y, ea.y, fmaf(va.x, ea.x, d0))));
                d1 = fmaf(vb.w, eb.w, fmaf(vb.z, eb.z, fmaf(vb.y, eb.y, fmaf(vb.x, eb.x, d1))));
                d2 = fmaf(vc.w, ec.w, fmaf(vc.z, ec.z, fmaf(vc.y, ec.y, fmaf(vc.x, ec.x, d2))));
                d3 = fmaf(vd.w, ed.w, fmaf(vd.z, ed.z, fmaf(vd.y, ed.y, fmaf(vd.x, ed.x, d3))));
            }
            float dot  = (d0 + d1) + (d2 + d3);
            float dist = fmaf(-2.f, dot, xnorm + enorm[k]);
            u64 pk = ((u64)ordf(dist) << 32) | (unsigned)k;
            if (pk < best) best = pk;          // dist-then-lowest-idx
        }
        red[tid] = best;
        __syncthreads();
        for (int s = 128; s > 0; s >>= 1) {
            if (tid < s) red[tid] = red[tid] < red[tid+s] ? red[tid] : red[tid+s];
            __syncthreads();
        }
        if (tid == 0) final_idx[n] = (unsigned)(red[0] & 0xFFFFFFFFu);
    }
}

// ------------------------------------------------------ gather + loss ------
__global__ __launch_bounds__(256) void vq_out(const float* __restrict__ x,
                                              const float* __restrict__ emb,
                                              const unsigned* __restrict__ final_idx,
                                              float* __restrict__ out,
                                              float* __restrict__ partial) {
    __shared__ int   lds_idx[256];
    __shared__ float lds_red[256];
    const int tid   = threadIdx.x;
    const int rbase = blockIdx.x * 256;
    const int n     = rbase + tid;

    lds_idx[tid] = (int)(final_idx[n] & 0xFFFFu);
    __syncthreads();

    const float4* x4 = (const float4*)x;
    const float4* e4 = (const float4*)emb;
    float4* o4 = (float4*)out;
    float err = 0.f;
    #pragma unroll
    for (int i = 0; i < 16; ++i) {
        int f = i * 256 + tid;
        int row = f >> 4, col = f & 15;
        int e = lds_idx[row];
        float4 q = e4[(size_t)e * 16 + col];
        float4 v = x4[(size_t)rbase * 16 + f];
        float ax = q.x - v.x, ay = q.y - v.y, az = q.z - v.z, aw = q.w - v.w;
        err += ax * ax + ay * ay + az * az + aw * aw;
        o4[(size_t)rbase * 16 + f] = q;
    }
    __syncthreads();
    lds_red[tid] = err;
    __syncthreads();
    for (int s = 128; s > 0; s >>= 1) {
        if (tid < s) lds_red[tid] += lds_red[tid + s];
        __syncthreads();
    }
    if (tid == 0) partial[blockIdx.x] = lds_red[0];
}

// ------------------------------------------------------------- finalize ----
__global__ __launch_bounds__(256) void vq_finish(const float* __restrict__ partial,
                                                 float* __restrict__ loss_out) {
    __shared__ float lds[256];
    int tid = threadIdx.x;
    lds[tid] = partial[tid];
    __syncthreads();
    for (int s = 128; s > 0; s >>= 1) {
        if (tid < s) lds[tid] += lds[tid + s];
        __syncthreads();
    }
    if (tid == 0) loss_out[0] = (1.0f + BETA) * lds[0] / (float)(NROWS * D);
}

// ---------------------------------------------------------------- launch ---
extern "C" void kernel_launch(void* const* d_in, const int* in_sizes, int n_in,
                              void* d_out, int out_size, void* d_ws, size_t ws_size,
                              hipStream_t stream) {
    const float* x   = (const float*)d_in[0];
    const float* emb = (const float*)d_in[1];
    float* out = (float*)d_out;
    char* ws = (char*)d_ws;

    char* Bp          = ws + WS_BP;
    float* enorm      = (float*)(ws + WS_EN);
    unsigned* fid     = (unsigned*)(ws + WS_FID);
    unsigned* list    = (unsigned*)(ws + WS_LIST);
    unsigned* counter = (unsigned*)(ws + WS_CNT);
    float* partial    = (float*)(ws + WS_PART);

    vq_prep<<<K / 256, 256, 0, stream>>>(emb, enorm, Bp, counter);
    vq_gemm<<<NROWS / BR, 256, 0, stream>>>(x, Bp, enorm, fid, list, counter);
    vq_fallback<<<128, 256, 0, stream>>>(x, emb, enorm, list, counter, fid);
    vq_out<<<NROWS / 256, 256, 0, stream>>>(x, emb, fid, out, partial);
    vq_finish<<<1, 256, 0, stream>>>(partial, out + (size_t)NROWS * D);
}

// Round 18
// 61.786 us; speedup vs baseline: 2.0990x; 1.3269x over previous
//
#include <hip/hip_runtime.h>
#include <math.h>

#define NROWS 65536
#define D     64
#define K     1024
#define NCT   8            // code tiles (K/128)
#define BR    128
#define BC    128
#define BETA  0.25f
#define SCALE 1024.0f      // pow2 -> exact f32 scaling; keeps xl/el f16-normal
#define THR   200.0f       // scaled-dist margin (R15-proven)

typedef _Float16 half8  __attribute__((ext_vector_type(8)));
typedef float    f32x4  __attribute__((ext_vector_type(4)));
typedef unsigned long long u64;

// ws layout (bytes)
// Bp: per code-tile ct, a 32 KB block that is the EXACT LDS image:
//   [bh 16 KB: row r (0..127) x chunk c' (16B), c' = c ^ (r&7)][bl 16 KB same]
#define WS_BP   0u                         // 8 tiles x 32 KB = 256 KB
#define WS_EN   (256u*1024)                // f32 [K] enorm (4 KB)
#define WS_EN2  (260u*1024)                // f32 [K] enorm*S^2 (4 KB)
#define WS_FID  (264u*1024)                // u32 [NROWS] (256 KB)
#define WS_LIST (WS_FID + 256u*1024)       // u32 [NROWS] (256 KB)
#define WS_CNT  (WS_LIST + 256u*1024)      // u32 counter
#define WS_PART (WS_CNT + 256u)            // f32 [256]

static __device__ __forceinline__ unsigned ordf(float f) {
    unsigned b = __float_as_uint(f);
    return (b & 0x80000000u) ? ~b : (b | 0x80000000u);
}
static __device__ __forceinline__ void gload_lds16(const void* g, void* l) {
    __builtin_amdgcn_global_load_lds(
        (const __attribute__((address_space(1))) unsigned*)g,
        (__attribute__((address_space(3))) unsigned*)l,
        16, 0, 0);
}

// ------------------- prep: enorm + swizzled/tiled packed B + counter reset --
__global__ __launch_bounds__(256) void vq_prep(const float* __restrict__ emb,
                                               float* __restrict__ enorm,
                                               float* __restrict__ enorm2,
                                               char* __restrict__ Bp,
                                               unsigned* __restrict__ counter) {
    if (blockIdx.x == 0 && threadIdx.x == 0) counter[0] = 0u;   // fresh each launch
    int k = blockIdx.x * 256 + threadIdx.x;
    if (k >= K) return;
    const int ct = k >> 7, r = k & 127;
    char* base = Bp + (size_t)ct * 32768 + (size_t)r * 128;
    const float4* e4 = (const float4*)(emb + (size_t)k * D);
    float s = 0.f;
    #pragma unroll
    for (int c = 0; c < 8; ++c) {              // chunk c = f16 elems 8c..8c+7
        float4 ea = e4[2 * c], eb = e4[2 * c + 1];
        s += ea.x * ea.x + ea.y * ea.y + ea.z * ea.z + ea.w * ea.w;   // R1-order
        s += eb.x * eb.x + eb.y * eb.y + eb.z * eb.z + eb.w * eb.w;
        float sc[8] = {ea.x * SCALE, ea.y * SCALE, ea.z * SCALE, ea.w * SCALE,
                       eb.x * SCALE, eb.y * SCALE, eb.z * SCALE, eb.w * SCALE};
        half8 hh, hl;
        #pragma unroll
        for (int e = 0; e < 8; ++e) {
            _Float16 h = (_Float16)sc[e];
            hh[e] = h;
            hl[e] = (_Float16)(sc[e] - (float)h);
        }
        int off = ((c ^ (r & 7)) << 4);
        *(half8*)(base + off)         = hh;     // eh
        *(half8*)(base + 16384 + off) = hl;     // el
    }
    enorm[k]  = s;
    enorm2[k] = s * (SCALE * SCALE);           // pow2 mul: exact
}

// --------------- MFMA filter: BR=128, dbuf LDS via global_load_lds, A in regs
// R18 changes vs R17 (passed, 70us, VALU-bound at 46%):
//  (a) epilogue = plain-f32 streaming top-2 (d1,d2,i1): ~6 VALU/candidate vs
//      ~13 for the u64 tournament (no ordf, no 64-bit cndmask chains).
//      Distances identical (fmaf(-2,acc,en2)); ci/ct ascending strict < ->
//      same tiebreak; exact cross-lane ties fail margin -> fallback (exact).
//  (b) MFMA issue order: 8 independent ah*bh, then al*bh, then ah*bl --
//      dependent-pair distance 1 -> 8.
//  (c) enorm*S^2 pretabulated (enorm2).
__global__ __launch_bounds__(256, 2) void vq_gemm(const float* __restrict__ x,
                                                  const char* __restrict__ Bp,
                                                  const float* __restrict__ enorm2,
                                                  unsigned* __restrict__ fid,
                                                  unsigned* __restrict__ list,
                                                  unsigned* __restrict__ counter) {
    __shared__ __align__(16) char bufB[2][32768];   // 64 KB double buffer

    const int tid  = threadIdx.x;
    const int lane = tid & 63, w = tid >> 6;
    const int fr   = lane & 15;                // frag row (A) / frag col (B)
    const int kg   = lane >> 4;                // k-group 0..3
    const int rb   = (int)blockIdx.x * BR;

    // ---- A fragments: direct global load + scale/split in registers ----
    const float4* x4 = (const float4*)x;
    half8 ah[2][2], al[2][2];
    #pragma unroll
    for (int fi = 0; fi < 2; ++fi) {
        #pragma unroll
        for (int kk = 0; kk < 2; ++kk) {
            int row = rb + w * 32 + fi * 16 + fr;
            float4 v0 = x4[(size_t)row * 16 + kk * 8 + kg * 2];
            float4 v1 = x4[(size_t)row * 16 + kk * 8 + kg * 2 + 1];
            float sc[8] = {v0.x * SCALE, v0.y * SCALE, v0.z * SCALE, v0.w * SCALE,
                           v1.x * SCALE, v1.y * SCALE, v1.z * SCALE, v1.w * SCALE};
            #pragma unroll
            for (int e = 0; e < 8; ++e) {
                _Float16 h = (_Float16)sc[e];
                ah[fi][kk][e] = h;
                al[fi][kk][e] = (_Float16)(sc[e] - (float)h);
            }
        }
    }

    // ---- prefetch B tile 0 ----
    {
        const char* gsrc = Bp + (size_t)w * 8192 + (size_t)lane * 16;
        char* ldst = &bufB[0][w * 8192];
        #pragma unroll
        for (int j = 0; j < 8; ++j)
            gload_lds16(gsrc + j * 1024, ldst + j * 1024);
    }

    // running top-2 state per (fi,rg): exact f32 dists + best idx
    float d1[2][4], d2[2][4];
    int   i1[2][4];
    #pragma unroll
    for (int fi = 0; fi < 2; ++fi)
        #pragma unroll
        for (int rg = 0; rg < 4; ++rg) {
            d1[fi][rg] = 3.4e38f; d2[fi][rg] = 3.4e38f; i1[fi][rg] = 0;
        }

    for (int ct = 0; ct < NCT; ++ct) {
        const int  cb  = ct * BC;
        const int  buf = ct & 1;
        __syncthreads();                       // drains B(ct) gl_lds; separates buf reuse

        if (ct < NCT - 1) {                    // prefetch B(ct+1), lands by next barrier
            const char* gsrc = Bp + (size_t)(ct + 1) * 32768 + (size_t)w * 8192
                             + (size_t)lane * 16;
            char* ldst = &bufB[buf ^ 1][w * 8192];
            #pragma unroll
            for (int j = 0; j < 8; ++j)
                gload_lds16(gsrc + j * 1024, ldst + j * 1024);
        }

        float en2f[8];
        #pragma unroll
        for (int ci = 0; ci < 8; ++ci)         // per-lane, L1/L2-cached
            en2f[ci] = enorm2[cb + ci * 16 + fr];
        const int idxb = cb + fr;

        const char* bb = &bufB[buf][0];

        #pragma unroll
        for (int g = 0; g < 2; ++g) {          // ci-groups of 4 (caps VGPR)
            f32x4 acc[2][4];
            #pragma unroll
            for (int fi = 0; fi < 2; ++fi)
                #pragma unroll
                for (int i = 0; i < 4; ++i) acc[fi][i] = (f32x4){0.f, 0.f, 0.f, 0.f};

            #pragma unroll
            for (int kk = 0; kk < 2; ++kk) {
                const int chunk = ((kk * 4 + kg) ^ (fr & 7)) << 4;
                half8 bf[4];
                #pragma unroll
                for (int i = 0; i < 4; ++i)    // bh frags (swizzled, conflict-free)
                    bf[i] = *(const half8*)(bb + ((g * 4 + i) * 16 + fr) * 128 + chunk);
                #pragma unroll                 // 8 independent, then dependents at dist 8
                for (int fi = 0; fi < 2; ++fi)
                    #pragma unroll
                    for (int i = 0; i < 4; ++i)
                        acc[fi][i] = __builtin_amdgcn_mfma_f32_16x16x32_f16(ah[fi][kk], bf[i], acc[fi][i], 0, 0, 0);
                #pragma unroll
                for (int fi = 0; fi < 2; ++fi)
                    #pragma unroll
                    for (int i = 0; i < 4; ++i)
                        acc[fi][i] = __builtin_amdgcn_mfma_f32_16x16x32_f16(al[fi][kk], bf[i], acc[fi][i], 0, 0, 0);
                #pragma unroll
                for (int i = 0; i < 4; ++i)    // bl frags
                    bf[i] = *(const half8*)(bb + 16384 + ((g * 4 + i) * 16 + fr) * 128 + chunk);
                #pragma unroll
                for (int fi = 0; fi < 2; ++fi)
                    #pragma unroll
                    for (int i = 0; i < 4; ++i)
                        acc[fi][i] = __builtin_amdgcn_mfma_f32_16x16x32_f16(ah[fi][kk], bf[i], acc[fi][i], 0, 0, 0);
            }

            // f32 streaming top-2 update (ci ascending; strict < tiebreak)
            #pragma unroll
            for (int fi = 0; fi < 2; ++fi) {
                #pragma unroll
                for (int rg = 0; rg < 4; ++rg) {
                    #pragma unroll
                    for (int i = 0; i < 4; ++i) {
                        float d  = fmaf(-2.f, acc[fi][i][rg], en2f[g * 4 + i]);
                        int  idx = idxb + (g * 4 + i) * 16;
                        bool lt  = d < d1[fi][rg];
                        d2[fi][rg] = fminf(fmaxf(d1[fi][rg], d), d2[fi][rg]);
                        i1[fi][rg] = lt ? idx : i1[fi][rg];
                        d1[fi][rg] = fminf(d1[fi][rg], d);
                    }
                }
            }
        }
    }

    // final: f32 butterfly top-2 across the 16 fr lanes, margin test, write
    #pragma unroll
    for (int fi = 0; fi < 2; ++fi) {
        #pragma unroll
        for (int rg = 0; rg < 4; ++rg) {
            float v1 = d1[fi][rg], v2 = d2[fi][rg];
            int   ii = i1[fi][rg];
            #pragma unroll
            for (int off = 8; off >= 1; off >>= 1) {
                float o1 = __shfl_xor(v1, off, 16);
                float o2 = __shfl_xor(v2, off, 16);
                int   oi = __shfl_xor(ii, off, 16);
                float loser = fmaxf(v1, o1);            // loser of the two firsts
                v2 = fminf(fminf(v2, o2), loser);
                bool bt = o1 < v1;                      // exact ties -> margin fails anyway
                v1 = fminf(v1, o1);
                ii = bt ? oi : ii;
            }
            if (fr == 0) {
                int row = rb + w * 32 + fi * 16 + kg * 4 + rg;
                if (v2 - v1 > THR) {
                    fid[row] = (unsigned)ii;            // provably ref argmin
                } else {
                    unsigned pos = atomicAdd(counter, 1u);
                    list[pos] = (unsigned)row;
                }
            }
        }
    }
}

// --------------------------- exact fallback: full 1024-code scan, R1 form ---
__global__ __launch_bounds__(256) void vq_fallback(const float* __restrict__ x,
                                                   const float* __restrict__ emb,
                                                   const float* __restrict__ enorm,
                                                   const unsigned* __restrict__ list,
                                                   const unsigned* __restrict__ counter,
                                                   unsigned* __restrict__ final_idx) {
    __shared__ float4 xr[16];
    __shared__ u64 red[256];
    const int tid = threadIdx.x;
    const unsigned total = counter[0];
    for (unsigned i = blockIdx.x; i < total; i += gridDim.x) {
        const int n = (int)list[i];
        __syncthreads();
        if (tid < 16) xr[tid] = ((const float4*)x)[(size_t)n * 16 + tid];
        __syncthreads();
        float xnorm = 0.f;                     // R1-order xnorm
        #pragma unroll
        for (int q = 0; q < 16; ++q) {
            float4 v = xr[q];
            xnorm += v.x * v.x + v.y * v.y + v.z * v.z + v.w * v.w;
        }
        u64 best = ~0ull;
        #pragma unroll
        for (int j = 0; j < 4; ++j) {
            int k = tid + j * 256;
            const float4* e4 = (const float4*)(emb + (size_t)k * D);
            float d0 = 0.f, d1v = 0.f, d2v = 0.f, d3v = 0.f;
            #pragma unroll
            for (int q = 0; q < 4; ++q) {      // proven R1 4-chain ordering
                float4 ea = e4[q*4+0], eb = e4[q*4+1], ec = e4[q*4+2], ed = e4[q*4+3];
                float4 va = xr[q*4+0], vb = xr[q*4+1], vc = xr[q*4+2], vd = xr[q*4+3];
                d0  = fmaf(va.w, ea.w, fmaf(va.z, ea.z, fmaf(va.y, ea.y, fmaf(va.x, ea.x, d0))));
                d1v = fmaf(vb.w, eb.w, fmaf(vb.z, eb.z, fmaf(vb.y, eb.y, fmaf(vb.x, eb.x, d1v))));
                d2v = fmaf(vc.w, ec.w, fmaf(vc.z, ec.z, fmaf(vc.y, ec.y, fmaf(vc.x, ec.x, d2v))));
                d3v = fmaf(vd.w, ed.w, fmaf(vd.z, ed.z, fmaf(vd.y, ed.y, fmaf(vd.x, ed.x, d3v))));
            }
            float dot  = (d0 + d1v) + (d2v + d3v);
            float dist = fmaf(-2.f, dot, xnorm + enorm[k]);
            u64 pk = ((u64)ordf(dist) << 32) | (unsigned)k;
            if (pk < best) best = pk;          // dist-then-lowest-idx
        }
        red[tid] = best;
        __syncthreads();
        for (int s = 128; s > 0; s >>= 1) {
            if (tid < s) red[tid] = red[tid] < red[tid+s] ? red[tid] : red[tid+s];
            __syncthreads();
        }
        if (tid == 0) final_idx[n] = (unsigned)(red[0] & 0xFFFFFFFFu);
    }
}

// ------------------------------------------------------ gather + loss ------
__global__ __launch_bounds__(256) void vq_out(const float* __restrict__ x,
                                              const float* __restrict__ emb,
                                              const unsigned* __restrict__ final_idx,
                                              float* __restrict__ out,
                                              float* __restrict__ partial) {
    __shared__ int   lds_idx[256];
    __shared__ float lds_red[256];
    const int tid   = threadIdx.x;
    const int rbase = blockIdx.x * 256;
    const int n     = rbase + tid;

    lds_idx[tid] = (int)(final_idx[n] & 0xFFFFu);
    __syncthreads();

    const float4* x4 = (const float4*)x;
    const float4* e4 = (const float4*)emb;
    float4* o4 = (float4*)out;
    float err = 0.f;
    #pragma unroll
    for (int i = 0; i < 16; ++i) {
        int f = i * 256 + tid;
        int row = f >> 4, col = f & 15;
        int e = lds_idx[row];
        float4 q = e4[(size_t)e * 16 + col];
        float4 v = x4[(size_t)rbase * 16 + f];
        float ax = q.x - v.x, ay = q.y - v.y, az = q.z - v.z, aw = q.w - v.w;
        err += ax * ax + ay * ay + az * az + aw * aw;
        o4[(size_t)rbase * 16 + f] = q;
    }
    __syncthreads();
    lds_red[tid] = err;
    __syncthreads();
    for (int s = 128; s > 0; s >>= 1) {
        if (tid < s) lds_red[tid] += lds_red[tid + s];
        __syncthreads();
    }
    if (tid == 0) partial[blockIdx.x] = lds_red[0];
}

// ------------------------------------------------------------- finalize ----
__global__ __launch_bounds__(256) void vq_finish(const float* __restrict__ partial,
                                                 float* __restrict__ loss_out) {
    __shared__ float lds[256];
    int tid = threadIdx.x;
    lds[tid] = partial[tid];
    __syncthreads();
    for (int s = 128; s > 0; s >>= 1) {
        if (tid < s) lds[tid] += lds[tid + s];
        __syncthreads();
    }
    if (tid == 0) loss_out[0] = (1.0f + BETA) * lds[0] / (float)(NROWS * D);
}

// ---------------------------------------------------------------- launch ---
extern "C" void kernel_launch(void* const* d_in, const int* in_sizes, int n_in,
                              void* d_out, int out_size, void* d_ws, size_t ws_size,
                              hipStream_t stream) {
    const float* x   = (const float*)d_in[0];
    const float* emb = (const float*)d_in[1];
    float* out = (float*)d_out;
    char* ws = (char*)d_ws;

    char* Bp          = ws + WS_BP;
    float* enorm      = (float*)(ws + WS_EN);
    float* enorm2     = (float*)(ws + WS_EN2);
    unsigned* fid     = (unsigned*)(ws + WS_FID);
    unsigned* list    = (unsigned*)(ws + WS_LIST);
    unsigned* counter = (unsigned*)(ws + WS_CNT);
    float* partial    = (float*)(ws + WS_PART);

    vq_prep<<<K / 256, 256, 0, stream>>>(emb, enorm, enorm2, Bp, counter);
    vq_gemm<<<NROWS / BR, 256, 0, stream>>>(x, Bp, enorm2, fid, list, counter);
    vq_fallback<<<128, 256, 0, stream>>>(x, emb, enorm, list, counter, fid);
    vq_out<<<NROWS / 256, 256, 0, stream>>>(x, emb, fid, out, partial);
    vq_finish<<<1, 256, 0, stream>>>(partial, out + (size_t)NROWS * D);
}